// Round 1
// baseline (263.894 us; speedup 1.0000x reference)
//
#include <hip/hip_runtime.h>

#define CIN 128
#define CHID 64
#define CSTRIDE 64   // csr row capacity; deg ~ Poisson(16), P(deg>64) ~ 1e-59

__device__ __forceinline__ float leaky(float v) { return v >= 0.f ? v : 0.01f * v; }
__device__ __forceinline__ float bcast(float v, int k) {
    return __int_as_float(__builtin_amdgcn_readlane(__float_as_int(v), k));
}
__device__ __forceinline__ void acc4(float4& a, const float4 v) {
    a.x += v.x; a.y += v.y; a.z += v.z; a.w += v.w;
}

// ---- XCD-sharded CSR build: shard s = blockIdx%8 owns dst range
//      [s*nps, s*nps+nps); each csr line is written by exactly ONE XCD. ----
__global__ void k_deg(const int* __restrict__ dst, const int* __restrict__ src,
                      int* __restrict__ deg, unsigned short* __restrict__ csr,
                      int E, int nps, int N) {
    const int shard = blockIdx.x & 7;
    const int chunk = blockIdx.x >> 3;
    const int nchunks = gridDim.x >> 3;
    const int lo = shard * nps;
    const int hi = min(lo + nps, N);
    const int estride = nchunks * 256;
    for (int e = chunk * 256 + threadIdx.x; e < E; e += estride) {
        int d = dst[e];
        if (d >= lo && d < hi) {
            int slot = atomicAdd(&deg[d], 1);
            if (slot < CSTRIDE) csr[(d << 6) + slot] = (unsigned short)src[e];
        }
    }
}

// ---- layer1 GEMM: hp1 = rsqrt(deg+1) * (x @ W1); W col in regs, x via readlane.
//      Output written in SHARDED layout [4][N][16] for the L2-resident gather. ----
__global__ __launch_bounds__(256) void k_gemm1(
    const float* __restrict__ x, const float* __restrict__ W,
    const int* __restrict__ deg, float* __restrict__ hps, int N) {
    const int wave = threadIdx.x >> 6, lane = threadIdx.x & 63;
    float w[CIN];
#pragma unroll
    for (int k = 0; k < CIN; ++k) w[k] = W[k * CHID + lane];
    float* __restrict__ op = hps + (size_t)(lane >> 4) * N * 16 + (lane & 15);
    const int stride = gridDim.x * 4;
    for (int n = blockIdx.x * 4 + wave; n < N; n += stride) {
        float x0 = x[(size_t)n * CIN + lane];
        float x1 = x[(size_t)n * CIN + 64 + lane];
        float acc0 = 0.f, acc1 = 0.f;
#pragma unroll
        for (int k = 0; k < 64; k += 2) {
            acc0 = fmaf(bcast(x0, k),     w[k],     acc0);
            acc1 = fmaf(bcast(x0, k + 1), w[k + 1], acc1);
        }
#pragma unroll
        for (int k = 0; k < 64; k += 2) {
            acc0 = fmaf(bcast(x1, k),     w[64 + k],     acc0);
            acc1 = fmaf(bcast(x1, k + 1), w[64 + k + 1], acc1);
        }
        float dn = rsqrtf((float)(deg[n] + 1));
        op[(size_t)n * 16] = dn * (acc0 + acc1);
    }
}

// ---- XCD-pinned channel-sharded aggregation.
//      blockIdx&7 -> (shard = cg>>1 in 0..3, node-half = cg&1).
//      Each XCD gathers ONLY from its shard's 3.2 MB region -> L2-resident.
//      One node row per shard = 16 floats = exactly one 64B line.
//      Lanes: q = lane&3 (float4 within row), g = lane>>2 (16 csr slots).
//      Writes raw sums (self + neighbors) into hagg[N][64]. ----
__global__ __launch_bounds__(256) void kAgg(
    const unsigned short* __restrict__ csr, const int* __restrict__ deg,
    const float* __restrict__ hps, float* __restrict__ hagg, int N) {
    const int wave = threadIdx.x >> 6, lane = threadIdx.x & 63;
    const int q = lane & 3, g = lane >> 2;
    const int cg = blockIdx.x & 7;          // XCD id (heuristic; correctness-free)
    const int sh = cg >> 1;                 // channel shard 0..3
    const int sub = cg & 1;                 // node half
    const int nchunks = gridDim.x >> 3;
    const int half = (N + 1) >> 1;
    const int lo = sub * half;
    const int hi = min(lo + half, N);
    const float4* __restrict__ hpq = (const float4*)(hps + (size_t)sh * N * 16);
    const int stride = nchunks * 4;
    const int n0 = lo + (blockIdx.x >> 3) * 4 + wave;
    int d = 0, c0 = 0;
    if (n0 < hi) { d = deg[n0]; c0 = csr[(n0 << 6) + g]; }   // prefetch 1 iter ahead
    for (int n = n0; n < hi; n += stride) {
        const int n2 = n + stride;
        int dN = 0, e0 = 0;
        if (n2 < hi) { dN = deg[n2]; e0 = csr[(n2 << 6) + g]; }
        const int dc = d;
        const int dcl = min(dc, CSTRIDE);   // loop bound clamp (buffer safety)
        const int base = n << 6;
        float4 a = make_float4(0.f, 0.f, 0.f, 0.f);
        if (g == 0) a = hpq[(size_t)n * 4 + q];              // self-loop term
        if (g < dcl) acc4(a, hpq[(size_t)c0 * 4 + q]);
        for (int b = g + 16; b < dcl; b += 16) {             // deg>16 tail (~43% of nodes)
            int s = csr[base + b];
            acc4(a, hpq[(size_t)s * 4 + q]);
        }
        // reduce over g (lane bits 2..5): strides 4,8,16,32
        a.x += __shfl_xor(a.x, 4, 64);  a.y += __shfl_xor(a.y, 4, 64);
        a.z += __shfl_xor(a.z, 4, 64);  a.w += __shfl_xor(a.w, 4, 64);
        a.x += __shfl_xor(a.x, 8, 64);  a.y += __shfl_xor(a.y, 8, 64);
        a.z += __shfl_xor(a.z, 8, 64);  a.w += __shfl_xor(a.w, 8, 64);
        a.x += __shfl_xor(a.x, 16, 64); a.y += __shfl_xor(a.y, 16, 64);
        a.z += __shfl_xor(a.z, 16, 64); a.w += __shfl_xor(a.w, 16, 64);
        a.x += __shfl_xor(a.x, 32, 64); a.y += __shfl_xor(a.y, 32, 64);
        a.z += __shfl_xor(a.z, 32, 64); a.w += __shfl_xor(a.w, 32, 64);
        if (g == 0) ((float4*)(hagg + (size_t)n * 64 + sh * 16))[q] = a;
        d = dN; c0 = e0;
    }
}

// ---- layer-1 epilogue + layer-2 GEMM: reads hagg[N][64] coalesced,
//      gv = leaky(dn*agg + b1), out = dn*(gv @ W2) written SHARDED for kAgg2. ----
__global__ __launch_bounds__(256) void kEpi1(
    const float* __restrict__ hagg, const int* __restrict__ deg,
    const float* __restrict__ b1, const float* __restrict__ W2,
    float* __restrict__ hps2, int N) {
    const int wave = threadIdx.x >> 6, lane = threadIdx.x & 63;
    float w[CHID];
#pragma unroll
    for (int k = 0; k < CHID; ++k) w[k] = W2[k * CHID + lane];
    const float bl = b1[lane];
    float* __restrict__ op = hps2 + (size_t)(lane >> 4) * N * 16 + (lane & 15);
    const int stride = gridDim.x * 4;
    for (int n = blockIdx.x * 4 + wave; n < N; n += stride) {
        float agg = hagg[(size_t)n * 64 + lane];
        float dn = rsqrtf((float)(deg[n] + 1));
        float v = leaky(dn * agg + bl);
        float acc0 = 0.f, acc1 = 0.f;
#pragma unroll
        for (int k = 0; k < 64; k += 2) {
            acc0 = fmaf(bcast(v, k),     w[k],     acc0);
            acc1 = fmaf(bcast(v, k + 1), w[k + 1], acc1);
        }
        op[(size_t)n * 16] = dn * (acc0 + acc1);
    }
}

// ---- layer-2 epilogue + W3 dot: hp3[n] = dn * sum_c leaky(dn*agg+b2[c])*W3[c] ----
__global__ __launch_bounds__(256) void kEpi2(
    const float* __restrict__ hagg, const int* __restrict__ deg,
    const float* __restrict__ b2, const float* __restrict__ W3,
    float* __restrict__ hp3, int N) {
    const int wave = threadIdx.x >> 6, lane = threadIdx.x & 63;
    const float bl = b2[lane], wl = W3[lane];
    const int stride = gridDim.x * 4;
    for (int n = blockIdx.x * 4 + wave; n < N; n += stride) {
        float dn = rsqrtf((float)(deg[n] + 1));
        float v = leaky(dn * hagg[(size_t)n * 64 + lane] + bl) * wl;
        v += __shfl_xor(v, 1, 64);  v += __shfl_xor(v, 2, 64);
        v += __shfl_xor(v, 4, 64);  v += __shfl_xor(v, 8, 64);
        v += __shfl_xor(v, 16, 64); v += __shfl_xor(v, 32, 64);
        if (lane == 0) hp3[n] = dn * v;
    }
}

// ---- layer3 aggregation + final epilogue: out[n] = dn*(hp3[n]+sum hp3[src]) + b3 ----
__global__ void kG3(const unsigned short* __restrict__ csr, const int* __restrict__ deg,
                    const float* __restrict__ hp3, const float* __restrict__ b3,
                    float* __restrict__ out, int N) {
    int t = blockIdx.x * 256 + threadIdx.x;
    int node = t >> 4, sl = t & 15;
    if (node >= N) return;
    int d = deg[node], base = node << 6;
    int dl = min(d, CSTRIDE);
    float acc = (sl == 0) ? hp3[node] : 0.f;
    for (int i = sl; i < dl; i += 16) acc += hp3[(int)csr[base + i]];
#pragma unroll
    for (int off = 8; off > 0; off >>= 1) acc += __shfl_down(acc, off, 16);
    if (sl == 0) out[node] = rsqrtf((float)(d + 1)) * acc + b3[0];
}

extern "C" void kernel_launch(void* const* d_in, const int* in_sizes, int n_in,
                              void* d_out, int out_size, void* d_ws, size_t ws_size,
                              hipStream_t stream) {
    const float* x  = (const float*)d_in[0];
    const int*   ei = (const int*)d_in[1];
    const float* W1 = (const float*)d_in[2];
    const float* b1 = (const float*)d_in[3];
    const float* W2 = (const float*)d_in[4];
    const float* b2 = (const float*)d_in[5];
    const float* W3 = (const float*)d_in[6];
    const float* b3 = (const float*)d_in[7];

    const int N = in_sizes[0] / CIN;     // 50000
    const int E = in_sizes[1] / 2;       // 800000
    const int* src = ei;
    const int* dst = ei + E;
    const int nps = (N + 7) / 8;         // nodes per XCD shard (csr build)

    // workspace carve-up (256B aligned) — ping-pong keeps total at ~32.4 MB
    char* w = (char*)d_ws;
    auto take = [&](size_t bytes) { char* p = w; w += (bytes + 255) & ~(size_t)255; return p; };
    int*            deg  = (int*)take((size_t)N * 4);
    unsigned short* csr  = (unsigned short*)take((size_t)N * CSTRIDE * 2);  // 6.4 MB
    float*          buf1 = (float*)take((size_t)N * CHID * 4);  // hp1s -> hp2s (sharded)
    float*          buf2 = (float*)take((size_t)N * CHID * 4);  // hagg1 -> hagg2
    float*          hp3  = (float*)take((size_t)N * 4);

    hipMemsetAsync(deg, 0, (size_t)N * 4, stream);

    k_deg  <<<2048, 256, 0, stream>>>(dst, src, deg, csr, E, nps, N);
    k_gemm1<<<1024, 256, 0, stream>>>(x, W1, deg, buf1, N);     // sharded hp1
    kAgg   <<<2048, 256, 0, stream>>>(csr, deg, buf1, buf2, N); // hagg1 (L2-resident gather)
    kEpi1  <<<2048, 256, 0, stream>>>(buf2, deg, b1, W2, buf1, N); // sharded hp2
    kAgg   <<<2048, 256, 0, stream>>>(csr, deg, buf1, buf2, N); // hagg2
    kEpi2  <<<2048, 256, 0, stream>>>(buf2, deg, b2, W3, hp3, N);
    kG3    <<<(N * 16 + 255) / 256, 256, 0, stream>>>(csr, deg, hp3, b3, (float*)d_out, N);
}

// Round 2
// 221.054 us; speedup vs baseline: 1.1938x; 1.1938x over previous
//
#include <hip/hip_runtime.h>

#define CIN 128
#define CHID 64
#define CSTRIDE 64   // csr row capacity; deg ~ Poisson(16), P(deg>64) ~ 1e-59

__device__ __forceinline__ float leaky(float v) { return v >= 0.f ? v : 0.01f * v; }
__device__ __forceinline__ float bcast(float v, int k) {
    return __int_as_float(__builtin_amdgcn_readlane(__float_as_int(v), k));
}
__device__ __forceinline__ void acc4(float4& a, const float4 v) {
    a.x += v.x; a.y += v.y; a.z += v.z; a.w += v.w;
}
__device__ __forceinline__ void xorred(float4& a) {
    a.x += __shfl_xor(a.x, 16, 64); a.y += __shfl_xor(a.y, 16, 64);
    a.z += __shfl_xor(a.z, 16, 64); a.w += __shfl_xor(a.w, 16, 64);
    a.x += __shfl_xor(a.x, 32, 64); a.y += __shfl_xor(a.y, 32, 64);
    a.z += __shfl_xor(a.z, 32, 64); a.w += __shfl_xor(a.w, 32, 64);
}

// ---- XCD-sharded CSR build: shard s = blockIdx%8 owns dst range
//      [s*nps, s*nps+nps); each csr line is written by exactly ONE XCD. ----
__global__ void k_deg(const int* __restrict__ dst, const int* __restrict__ src,
                      int* __restrict__ deg, unsigned short* __restrict__ csr,
                      int E, int nps, int N) {
    const int shard = blockIdx.x & 7;
    const int chunk = blockIdx.x >> 3;
    const int nchunks = gridDim.x >> 3;
    const int lo = shard * nps;
    const int hi = min(lo + nps, N);
    const int estride = nchunks * 256;
    for (int e = chunk * 256 + threadIdx.x; e < E; e += estride) {
        int d = dst[e];
        if (d >= lo && d < hi) {
            int slot = atomicAdd(&deg[d], 1);
            if (slot < CSTRIDE) csr[(d << 6) + slot] = (unsigned short)src[e];
        }
    }
}

// ---- layer1 GEMM: hp1 = rsqrt(deg+1) * (x @ W1); W col in regs, x via readlane ----
__global__ __launch_bounds__(256) void k_gemm1(
    const float* __restrict__ x, const float* __restrict__ W,
    const int* __restrict__ deg, float* __restrict__ hp, int N) {
    const int wave = threadIdx.x >> 6, lane = threadIdx.x & 63;
    float w[CIN];
#pragma unroll
    for (int k = 0; k < CIN; ++k) w[k] = W[k * CHID + lane];
    const int stride = gridDim.x * 4;
    for (int n = blockIdx.x * 4 + wave; n < N; n += stride) {
        float x0 = x[(size_t)n * CIN + lane];
        float x1 = x[(size_t)n * CIN + 64 + lane];
        float acc0 = 0.f, acc1 = 0.f;
#pragma unroll
        for (int k = 0; k < 64; k += 2) {
            acc0 = fmaf(bcast(x0, k),     w[k],     acc0);
            acc1 = fmaf(bcast(x0, k + 1), w[k + 1], acc1);
        }
#pragma unroll
        for (int k = 0; k < 64; k += 2) {
            acc0 = fmaf(bcast(x1, k),     w[64 + k],     acc0);
            acc1 = fmaf(bcast(x1, k + 1), w[64 + k + 1], acc1);
        }
        float dn = rsqrtf((float)(deg[n] + 1));
        hp[(size_t)n * CHID + lane] = dn * (acc0 + acc1);
    }
}

// ---- gather(hp1) + layer-1 epilogue + layer-2 GEMM, software-pipelined:
//      csr/deg 2 nodes ahead (8 slots -> deg<=32), gather payload (self +
//      slots 0..15) 1 node ahead, so load latency hides under the current
//      node's reduce + GEMM epilogue. ----
__global__ __launch_bounds__(256) void kG1(
    const unsigned short* __restrict__ csr, const int* __restrict__ deg,
    const float* __restrict__ hp, const float* __restrict__ W2,
    const float* __restrict__ b1, float* __restrict__ hp2, int N) {
    const int wave = threadIdx.x >> 6, lane = threadIdx.x & 63;
    const int g = lane >> 4, sl = lane & 15;
    float w[CHID];
#pragma unroll
    for (int k = 0; k < CHID; ++k) w[k] = W2[k * CHID + lane];
    const float4 bb = ((const float4*)b1)[sl];
    const float4* __restrict__ hpq = (const float4*)hp;
    const int stride = gridDim.x * 4;
    const int n0 = blockIdx.x * 4 + wave;
    const float4 z = make_float4(0.f, 0.f, 0.f, 0.f);

    int dA = 0, dB = 0;
    int cA[8], cB[8];
#pragma unroll
    for (int k = 0; k < 8; ++k) { cA[k] = 0; cB[k] = 0; }
    float4 pS = z, p0 = z, p1 = z, p2 = z, p3 = z;

    if (n0 < N) {                          // prologue
        dA = deg[n0];
        const int ba = n0 << 6;
#pragma unroll
        for (int k = 0; k < 8; ++k) cA[k] = csr[ba + g + 4 * k];
        const int n1 = n0 + stride;
        if (n1 < N) {
            dB = deg[n1];
            const int bbs = n1 << 6;
#pragma unroll
            for (int k = 0; k < 8; ++k) cB[k] = csr[bbs + g + 4 * k];
        }
        if (g == 0)      pS = hpq[(size_t)n0 * 16 + sl];
        if (g < dA)      p0 = hpq[(size_t)cA[0] * 16 + sl];
        if (g + 4 < dA)  p1 = hpq[(size_t)cA[1] * 16 + sl];
        if (g + 8 < dA)  p2 = hpq[(size_t)cA[2] * 16 + sl];
        if (g + 12 < dA) p3 = hpq[(size_t)cA[3] * 16 + sl];
    }

    for (int n = n0; n < N; n += stride) {
        const int nB = n + stride, nC = nB + stride;
        // --- stage 1: csr/deg for node n+2*stride
        int dC = 0; int cC[8];
#pragma unroll
        for (int k = 0; k < 8; ++k) cC[k] = 0;
        if (nC < N) {
            dC = deg[nC];
            const int bc = nC << 6;
#pragma unroll
            for (int k = 0; k < 8; ++k) cC[k] = csr[bc + g + 4 * k];
        }
        // --- stage 2: gather payload for node n+stride (consumed next iter)
        float4 qS = z, q0 = z, q1 = z, q2 = z, q3 = z;
        if (nB < N) {
            if (g == 0)      qS = hpq[(size_t)nB * 16 + sl];
            if (g < dB)      q0 = hpq[(size_t)cB[0] * 16 + sl];
            if (g + 4 < dB)  q1 = hpq[(size_t)cB[1] * 16 + sl];
            if (g + 8 < dB)  q2 = hpq[(size_t)cB[2] * 16 + sl];
            if (g + 12 < dB) q3 = hpq[(size_t)cB[3] * 16 + sl];
        }
        // --- stage 3: mid-tail (slots 16..31) for current node, indices resident
        const int dcl = min(dA, CSTRIDE);
        float4 t0 = z, t1 = z, t2 = z, t3 = z;
        if (g + 16 < dcl) t0 = hpq[(size_t)cA[4] * 16 + sl];
        if (g + 20 < dcl) t1 = hpq[(size_t)cA[5] * 16 + sl];
        if (g + 24 < dcl) t2 = hpq[(size_t)cA[6] * 16 + sl];
        if (g + 28 < dcl) t3 = hpq[(size_t)cA[7] * 16 + sl];
        // --- compute current node from prefetched registers
        float4 a0 = pS, a1 = p1, a2 = p2, a3 = p3;
        acc4(a0, p0); acc4(a1, t0); acc4(a2, t1); acc4(a3, t2);
        acc4(a0, t3);
        const int base = n << 6;
        for (int b = g + 32; b < dcl; b += 16) {     // deep tail, ~0.02% of nodes
            int s = csr[base + b];
            acc4(a1, hpq[(size_t)s * 16 + sl]);
        }
        acc4(a0, a1); acc4(a2, a3); acc4(a0, a2);
        xorred(a0);
        float dn = rsqrtf((float)(dA + 1));
        float4 gv;
        gv.x = leaky(dn * a0.x + bb.x);
        gv.y = leaky(dn * a0.y + bb.y);
        gv.z = leaky(dn * a0.z + bb.z);
        gv.w = leaky(dn * a0.w + bb.w);
        float acc0 = 0.f, acc1 = 0.f;
#pragma unroll
        for (int i = 0; i < 16; ++i) {
            acc0 = fmaf(bcast(gv.x, i), w[4 * i + 0], acc0);
            acc1 = fmaf(bcast(gv.y, i), w[4 * i + 1], acc1);
            acc0 = fmaf(bcast(gv.z, i), w[4 * i + 2], acc0);
            acc1 = fmaf(bcast(gv.w, i), w[4 * i + 3], acc1);
        }
        hp2[(size_t)n * CHID + lane] = dn * (acc0 + acc1);
        // --- rotate pipeline
        dA = dB; dB = dC;
#pragma unroll
        for (int k = 0; k < 8; ++k) { cA[k] = cB[k]; cB[k] = cC[k]; }
        pS = qS; p0 = q0; p1 = q1; p2 = q2; p3 = q3;
    }
}

// ---- gather(hp2) + layer-2 epilogue + W3 dot, same pipeline ----
__global__ __launch_bounds__(256) void kG2(
    const unsigned short* __restrict__ csr, const int* __restrict__ deg,
    const float* __restrict__ hp, const float* __restrict__ b2,
    const float* __restrict__ W3, float* __restrict__ hp3, int N) {
    const int wave = threadIdx.x >> 6, lane = threadIdx.x & 63;
    const int g = lane >> 4, sl = lane & 15;
    const float4 bb = ((const float4*)b2)[sl];
    const float4 w3 = ((const float4*)W3)[sl];
    const float4* __restrict__ hpq = (const float4*)hp;
    const int stride = gridDim.x * 4;
    const int n0 = blockIdx.x * 4 + wave;
    const float4 z = make_float4(0.f, 0.f, 0.f, 0.f);

    int dA = 0, dB = 0;
    int cA[8], cB[8];
#pragma unroll
    for (int k = 0; k < 8; ++k) { cA[k] = 0; cB[k] = 0; }
    float4 pS = z, p0 = z, p1 = z, p2 = z, p3 = z;

    if (n0 < N) {
        dA = deg[n0];
        const int ba = n0 << 6;
#pragma unroll
        for (int k = 0; k < 8; ++k) cA[k] = csr[ba + g + 4 * k];
        const int n1 = n0 + stride;
        if (n1 < N) {
            dB = deg[n1];
            const int bbs = n1 << 6;
#pragma unroll
            for (int k = 0; k < 8; ++k) cB[k] = csr[bbs + g + 4 * k];
        }
        if (g == 0)      pS = hpq[(size_t)n0 * 16 + sl];
        if (g < dA)      p0 = hpq[(size_t)cA[0] * 16 + sl];
        if (g + 4 < dA)  p1 = hpq[(size_t)cA[1] * 16 + sl];
        if (g + 8 < dA)  p2 = hpq[(size_t)cA[2] * 16 + sl];
        if (g + 12 < dA) p3 = hpq[(size_t)cA[3] * 16 + sl];
    }

    for (int n = n0; n < N; n += stride) {
        const int nB = n + stride, nC = nB + stride;
        int dC = 0; int cC[8];
#pragma unroll
        for (int k = 0; k < 8; ++k) cC[k] = 0;
        if (nC < N) {
            dC = deg[nC];
            const int bc = nC << 6;
#pragma unroll
            for (int k = 0; k < 8; ++k) cC[k] = csr[bc + g + 4 * k];
        }
        float4 qS = z, q0 = z, q1 = z, q2 = z, q3 = z;
        if (nB < N) {
            if (g == 0)      qS = hpq[(size_t)nB * 16 + sl];
            if (g < dB)      q0 = hpq[(size_t)cB[0] * 16 + sl];
            if (g + 4 < dB)  q1 = hpq[(size_t)cB[1] * 16 + sl];
            if (g + 8 < dB)  q2 = hpq[(size_t)cB[2] * 16 + sl];
            if (g + 12 < dB) q3 = hpq[(size_t)cB[3] * 16 + sl];
        }
        const int dcl = min(dA, CSTRIDE);
        float4 t0 = z, t1 = z, t2 = z, t3 = z;
        if (g + 16 < dcl) t0 = hpq[(size_t)cA[4] * 16 + sl];
        if (g + 20 < dcl) t1 = hpq[(size_t)cA[5] * 16 + sl];
        if (g + 24 < dcl) t2 = hpq[(size_t)cA[6] * 16 + sl];
        if (g + 28 < dcl) t3 = hpq[(size_t)cA[7] * 16 + sl];
        float4 a0 = pS, a1 = p1, a2 = p2, a3 = p3;
        acc4(a0, p0); acc4(a1, t0); acc4(a2, t1); acc4(a3, t2);
        acc4(a0, t3);
        const int base = n << 6;
        for (int b = g + 32; b < dcl; b += 16) {
            int s = csr[base + b];
            acc4(a1, hpq[(size_t)s * 16 + sl]);
        }
        acc4(a0, a1); acc4(a2, a3); acc4(a0, a2);
        xorred(a0);
        float dn = rsqrtf((float)(dA + 1));
        float t = leaky(dn * a0.x + bb.x) * w3.x
                + leaky(dn * a0.y + bb.y) * w3.y
                + leaky(dn * a0.z + bb.z) * w3.z
                + leaky(dn * a0.w + bb.w) * w3.w;
        t += __shfl_xor(t, 1, 64); t += __shfl_xor(t, 2, 64);
        t += __shfl_xor(t, 4, 64); t += __shfl_xor(t, 8, 64);
        if (lane == 0) hp3[n] = dn * t;
        dA = dB; dB = dC;
#pragma unroll
        for (int k = 0; k < 8; ++k) { cA[k] = cB[k]; cB[k] = cC[k]; }
        pS = qS; p0 = q0; p1 = q1; p2 = q2; p3 = q3;
    }
}

// ---- layer3 aggregation + final epilogue: out[n] = dn*(hp3[n]+sum hp3[src]) + b3 ----
__global__ void kG3(const unsigned short* __restrict__ csr, const int* __restrict__ deg,
                    const float* __restrict__ hp3, const float* __restrict__ b3,
                    float* __restrict__ out, int N) {
    int t = blockIdx.x * 256 + threadIdx.x;
    int node = t >> 4, sl = t & 15;
    if (node >= N) return;
    int d = deg[node], base = node << 6;
    int dl = min(d, CSTRIDE);
    float acc = (sl == 0) ? hp3[node] : 0.f;
    for (int i = sl; i < dl; i += 16) acc += hp3[(int)csr[base + i]];
#pragma unroll
    for (int off = 8; off > 0; off >>= 1) acc += __shfl_down(acc, off, 16);
    if (sl == 0) out[node] = rsqrtf((float)(d + 1)) * acc + b3[0];
}

extern "C" void kernel_launch(void* const* d_in, const int* in_sizes, int n_in,
                              void* d_out, int out_size, void* d_ws, size_t ws_size,
                              hipStream_t stream) {
    const float* x  = (const float*)d_in[0];
    const int*   ei = (const int*)d_in[1];
    const float* W1 = (const float*)d_in[2];
    const float* b1 = (const float*)d_in[3];
    const float* W2 = (const float*)d_in[4];
    const float* b2 = (const float*)d_in[5];
    const float* W3 = (const float*)d_in[6];
    const float* b3 = (const float*)d_in[7];

    const int N = in_sizes[0] / CIN;     // 50000
    const int E = in_sizes[1] / 2;       // 800000
    const int* src = ei;
    const int* dst = ei + E;
    const int nps = (N + 7) / 8;         // nodes per XCD shard

    // workspace carve-up (256B aligned)
    char* w = (char*)d_ws;
    auto take = [&](size_t bytes) { char* p = w; w += (bytes + 255) & ~(size_t)255; return p; };
    int*            deg = (int*)take((size_t)N * 4);
    unsigned short* csr = (unsigned short*)take((size_t)N * CSTRIDE * 2);  // 6.4 MB
    float*          A   = (float*)take((size_t)N * CHID * 4);              // hp1
    float*          B   = (float*)take((size_t)N * CHID * 4);              // hp2
    float*          hp3 = (float*)take((size_t)N * 4);

    hipMemsetAsync(deg, 0, (size_t)N * 4, stream);

    k_deg  <<<2048, 256, 0, stream>>>(dst, src, deg, csr, E, nps, N);
    k_gemm1<<<1024, 256, 0, stream>>>(x, W1, deg, A, N);
    kG1    <<<2048, 256, 0, stream>>>(csr, deg, A, W2, b1, B, N);
    kG2    <<<2048, 256, 0, stream>>>(csr, deg, B, b2, W3, hp3, N);
    kG3    <<<(N * 16 + 255) / 256, 256, 0, stream>>>(csr, deg, hp3, b3, (float*)d_out, N);
}